// Round 2
// baseline (686.184 us; speedup 1.0000x reference)
//
#include <hip/hip_runtime.h>

constexpr float kAlpha = 0.1f;
constexpr float kBeta  = 1.1f;
constexpr int   kC     = 16;
constexpr int   kD     = 512;
constexpr float kEps   = 1e-8f;

// ws layout (float offsets)
constexpr int SUMS_OFF = 0;       // kC*kD = 8192 floats
constexpr int CNT_OFF  = 8192;    // 16
constexpr int TOT_OFF  = 8208;    // 1
constexpr int CN_OFF   = 8224;    // 8192 (16B aligned)
constexpr int MSK_OFF  = 16416;   // 16 (unsigned)
constexpr int SCL_OFF  = 16432;   // [0]=denom, [1]=num_pairs
constexpr int ZERO_FLOATS = 8209; // sums + cnt + total

// ---------------------------------------------------------------- K1: class sums + counts
// Register-accumulator version: no LDS in the hot loop, 8-row unroll, branchless
// wave-uniform selects. Thread t owns dim t (512 threads = 512 dims).
__global__ __launch_bounds__(512) void k1_sums(const float* __restrict__ emb,
                                               const int* __restrict__ labels,
                                               float* __restrict__ sums,
                                               float* __restrict__ cnt,
                                               int N, int rpb) {
    int tid = threadIdx.x;           // = dim
    int myc = tid & 15;              // class this lane counts
    float acc[kC];
#pragma unroll
    for (int c = 0; c < kC; ++c) acc[c] = 0.f;
    float cacc = 0.f;

    int r0 = blockIdx.x * rpb;
    int r1 = min(r0 + rpb, N);
    int r = r0;
    for (; r + 8 <= r1; r += 8) {
        int4 la = *(const int4*)(labels + r);      // uniform -> s_load
        int4 lb = *(const int4*)(labels + r + 4);
        const float* e = emb + (size_t)r * kD + tid;
        float v0 = e[0 * kD];
        float v1 = e[1 * kD];
        float v2 = e[2 * kD];
        float v3 = e[3 * kD];
        float v4 = e[4 * kD];
        float v5 = e[5 * kD];
        float v6 = e[6 * kD];
        float v7 = e[7 * kD];
#pragma unroll
        for (int c = 0; c < kC; ++c) {
            float s = (la.x == c ? v0 : 0.f) + (la.y == c ? v1 : 0.f)
                    + (la.z == c ? v2 : 0.f) + (la.w == c ? v3 : 0.f)
                    + (lb.x == c ? v4 : 0.f) + (lb.y == c ? v5 : 0.f)
                    + (lb.z == c ? v6 : 0.f) + (lb.w == c ? v7 : 0.f);
            acc[c] += s;
        }
        cacc += (la.x == myc ? 1.f : 0.f) + (la.y == myc ? 1.f : 0.f)
              + (la.z == myc ? 1.f : 0.f) + (la.w == myc ? 1.f : 0.f)
              + (lb.x == myc ? 1.f : 0.f) + (lb.y == myc ? 1.f : 0.f)
              + (lb.z == myc ? 1.f : 0.f) + (lb.w == myc ? 1.f : 0.f);
    }
    for (; r < r1; ++r) {            // tail (unused at N=131072)
        int l = labels[r];
        float v = emb[(size_t)r * kD + tid];
#pragma unroll
        for (int c = 0; c < kC; ++c) acc[c] += (l == c ? v : 0.f);
        cacc += (l == myc ? 1.f : 0.f);
    }

#pragma unroll
    for (int c = 0; c < kC; ++c) atomicAdd(&sums[c * kD + tid], acc[c]);
    if (tid < kC) atomicAdd(&cnt[tid], cacc);
}

// ---------------------------------------------------------------- K2: centroids, pair logic (1 block)
__global__ __launch_bounds__(256) void k2_cent(const float* __restrict__ sums,
                                               const float* __restrict__ cnt_g,
                                               float* __restrict__ cn_g,
                                               unsigned* __restrict__ mask_g,
                                               float* __restrict__ scal) {
    __shared__ __align__(16) float lcn[kC * kD];  // 32 KB
    __shared__ float lcnt[kC];
    __shared__ float red[256];
    __shared__ float norms[kC];
    __shared__ float pdm[kC * kC];
    int tid = threadIdx.x;
    if (tid < kC) lcnt[tid] = cnt_g[tid];
    __syncthreads();

    int c = tid >> 4, sub = tid & 15;
    float invc = 1.f / fmaxf(lcnt[c], 1.f);
    float sq = 0.f;
    for (int d = sub; d < kD; d += 16) {
        float v = sums[c * kD + d] * invc;
        lcn[c * kD + d] = v;
        sq += v * v;
    }
    red[tid] = sq;
    __syncthreads();
    if (tid < kC) {
        float t = 0.f;
        for (int k = 0; k < 16; ++k) t += red[tid * 16 + k];
        norms[tid] = fmaxf(sqrtf(t), kEps);
    }
    __syncthreads();
    for (int i = tid; i < kC * kD; i += 256) {
        float v = lcn[i] / norms[i / kD];
        lcn[i] = v;
        cn_g[i] = v;
    }
    __syncthreads();
    int pi = tid >> 4, pj = tid & 15;
    float dot = 0.f;
    for (int dd = 0; dd < kD; ++dd) {
        int d = (dd + tid) & (kD - 1);
        dot += lcn[pi * kD + d] * lcn[pj * kD + d];
    }
    pdm[tid] = 1.f - dot;
    __syncthreads();
    if (tid == 0) {
        unsigned m[kC];
        for (int a = 0; a < kC; ++a) m[a] = 0u;
        float npairs = 0.f;
        for (int a = 0; a < kC; ++a)
            for (int b = a + 1; b < kC; ++b) {
                bool close = (pdm[a * kC + b] <= kBeta) && (lcnt[a] > 0.f) && (lcnt[b] > 0.f);
                if (close) { m[a] |= 1u << b; m[b] |= 1u << a; npairs += 1.f; }
            }
        float count = 0.f;
        for (int a = 0; a < kC; ++a) {
            mask_g[a] = m[a];
            count += (float)__popc(m[a]) * lcnt[a];
        }
        scal[0] = fmaxf(count, 1.f);
        scal[1] = npairs;
    }
}

// ---------------------------------------------------------------- K3: main distance pass
// Dim-slice layout: 16-lane group per row; lane j reads 256B-contiguous float4
// slices (coalesced), accumulates partial dots for all 16 classes, then a
// 4-level shfl_xor butterfly reduces within the group.
__global__ __launch_bounds__(256) void k3_main(const float* __restrict__ emb,
                                               const int* __restrict__ labels,
                                               const float* __restrict__ cn_g,
                                               const unsigned* __restrict__ mask_g,
                                               float* __restrict__ total,
                                               int N, int rpb) {
    __shared__ __align__(16) float lcn[kC * kD];  // 32 KB
    __shared__ unsigned lmask[kC];
    __shared__ float wsum[4];
    int tid = threadIdx.x;
    for (int i = tid; i < kC * kD; i += 256) lcn[i] = cn_g[i];
    if (tid < kC) lmask[tid] = mask_g[tid];
    __syncthreads();

    const int j = tid & 15;        // lane within group (dim slice)
    const int grp = tid >> 4;      // group 0..15 -> one row per pass
    const float4* w4 = (const float4*)lcn;

    float priv = 0.f;
    int r0 = blockIdx.x * rpb;
    int r1 = min(r0 + rpb, N);
    for (int rb = r0; rb < r1; rb += 16) {
        int r = rb + grp;
        bool valid = (r < r1);
        int rc = valid ? r : r0;                  // clamp for safe loads
        int lab = labels[rc];                     // prefetch label early
        const float4* x4 = (const float4*)(emb + (size_t)rc * kD);

        float dots[kC];
#pragma unroll
        for (int c = 0; c < kC; ++c) dots[c] = 0.f;
        float nrm = 0.f;

#pragma unroll
        for (int it = 0; it < kD / 64; ++it) {    // 8 iters
            float4 x = x4[it * 16 + j];
            nrm += x.x * x.x + x.y * x.y + x.z * x.z + x.w * x.w;
#pragma unroll
            for (int c = 0; c < kC; ++c) {
                float4 w = w4[c * (kD / 4) + it * 16 + j];
                dots[c] += x.x * w.x + x.y * w.y + x.z * w.z + x.w * w.w;
            }
        }

        // butterfly reduce across the 16 lanes of the group
#pragma unroll
        for (int m = 1; m < 16; m <<= 1) {
#pragma unroll
            for (int c = 0; c < kC; ++c) dots[c] += __shfl_xor(dots[c], m, 64);
            nrm += __shfl_xor(nrm, m, 64);
        }

        if (j == 0 && valid) {
            unsigned mm = lmask[lab];
            float inv = 1.f / fmaxf(sqrtf(nrm), kEps);
            float down = 0.f;
#pragma unroll
            for (int c = 0; c < kC; ++c) down = (c == lab) ? (1.f - dots[c] * inv) : down;
            float s = (float)__popc(mm) * fmaxf(down - kAlpha, 0.f);
#pragma unroll
            for (int c = 0; c < kC; ++c) {
                float dd = 1.f - dots[c] * inv;
                s += ((mm >> c) & 1u) ? fmaxf(kBeta - dd, 0.f) : 0.f;
            }
            priv += s;
        }
    }

    // block reduce
#pragma unroll
    for (int off = 32; off > 0; off >>= 1) priv += __shfl_down(priv, off, 64);
    if ((tid & 63) == 0) wsum[tid >> 6] = priv;
    __syncthreads();
    if (tid == 0) atomicAdd(total, wsum[0] + wsum[1] + wsum[2] + wsum[3]);
}

// ---------------------------------------------------------------- K4: epilogue
__global__ void k4_final(const float* __restrict__ total,
                         const float* __restrict__ scal,
                         float* __restrict__ out) {
    out[0] = (scal[1] > 0.f) ? (total[0] / scal[0]) : 0.f;
}

extern "C" void kernel_launch(void* const* d_in, const int* in_sizes, int n_in,
                              void* d_out, int out_size, void* d_ws, size_t ws_size,
                              hipStream_t stream) {
    const float* emb = (const float*)d_in[0];
    const int* labels = (const int*)d_in[1];
    int N = in_sizes[0] / kD;

    float* ws = (float*)d_ws;
    float* sums = ws + SUMS_OFF;
    float* cnt = ws + CNT_OFF;
    float* total = ws + TOT_OFF;
    float* cn = ws + CN_OFF;
    unsigned* mask = (unsigned*)(ws + MSK_OFF);
    float* scal = ws + SCL_OFF;

    hipMemsetAsync(d_ws, 0, ZERO_FLOATS * sizeof(float), stream);

    int blocks1 = 512;
    int rpb1 = (N + blocks1 - 1) / blocks1;
    k1_sums<<<blocks1, 512, 0, stream>>>(emb, labels, sums, cnt, N, rpb1);

    k2_cent<<<1, 256, 0, stream>>>(sums, cnt, cn, mask, scal);

    int blocks3 = 512;
    int rpb3 = (N + blocks3 - 1) / blocks3;
    k3_main<<<blocks3, 256, 0, stream>>>(emb, labels, cn, mask, total, N, rpb3);

    k4_final<<<1, 1, 0, stream>>>(total, scal, (float*)d_out);
}

// Round 3
// 557.157 us; speedup vs baseline: 1.2316x; 1.2316x over previous
//
#include <hip/hip_runtime.h>

constexpr float kAlpha = 0.1f;
constexpr float kBeta  = 1.1f;
constexpr int   kC     = 16;
constexpr int   kD     = 512;
constexpr float kEps   = 1e-8f;

// ws layout (float offsets)
constexpr int SUMS_OFF = 0;       // kC*kD = 8192 floats
constexpr int CNT_OFF  = 8192;    // 16
constexpr int TOT_OFF  = 8208;    // 1
constexpr int CN_OFF   = 8224;    // 8192 (16B aligned)
constexpr int MSK_OFF  = 16416;   // 16 (unsigned)
constexpr int SCL_OFF  = 16432;   // [0]=denom, [1]=num_pairs
constexpr int ZERO_FLOATS = 8209; // sums + cnt + total

__device__ __forceinline__ float dot4(float4 a, float4 b) {
    return a.x * b.x + a.y * b.y + a.z * b.z + a.w * b.w;
}

// ---------------------------------------------------------------- K1: class sums + counts
// Wave-per-half-row: label is wave-uniform -> uniform 16-way select into
// float4 register accumulators. float4 global loads (16B/lane). LDS only at flush.
__global__ __launch_bounds__(512) void k1_sums(const float* __restrict__ emb,
                                               const int* __restrict__ labels,
                                               float* __restrict__ sums,
                                               float* __restrict__ cnt,
                                               int N, int rpb) {
    __shared__ float lacc[kC * kD];   // 32 KB
    __shared__ float lcnt[kC];
    int tid = threadIdx.x;
    int wave = tid >> 6, lane = tid & 63;
    int half = wave & 1;              // this wave always handles dims [half*256, half*256+256)

    for (int i = tid; i < kC * kD; i += 512) lacc[i] = 0.f;
    if (tid < kC) lcnt[tid] = 0.f;
    __syncthreads();

    float4 acc[kC];
#pragma unroll
    for (int c = 0; c < kC; ++c) acc[c] = make_float4(0.f, 0.f, 0.f, 0.f);
    float cacc = 0.f;

    const float4* e4 = (const float4*)emb;
    // half-row units: h in [2*r0, 2*r1); row = h>>1, half = h&1
    long long h0 = 2LL * blockIdx.x * rpb;
    long long hEnd = min(h0 + 2LL * rpb, 2LL * (long long)N);

    for (long long h = h0 + wave; h < hEnd; h += 16) {
        long long hb = h + 8;
        bool vb = (hb < hEnd);
        int rowA = (int)(h >> 1);
        int rowB = vb ? (int)(hb >> 1) : rowA;
        int lA = labels[rowA];
        int lB = labels[rowB];
        float4 vA = e4[(size_t)rowA * 128 + half * 64 + lane];
        float4 vB = e4[(size_t)rowB * 128 + half * 64 + lane];
        if (!vb) vB = make_float4(0.f, 0.f, 0.f, 0.f);
#pragma unroll
        for (int c = 0; c < kC; ++c) {
            if (lA == c) { acc[c].x += vA.x; acc[c].y += vA.y; acc[c].z += vA.z; acc[c].w += vA.w; }
            if (lB == c) { acc[c].x += vB.x; acc[c].y += vB.y; acc[c].z += vB.z; acc[c].w += vB.w; }
        }
        if (half == 0 && lane < kC) {
            cacc += (lA == lane ? 1.f : 0.f) + ((vb && lB == lane) ? 1.f : 0.f);
        }
    }

    // flush registers -> LDS (atomic across the block's waves)
#pragma unroll
    for (int c = 0; c < kC; ++c) {
        float* p = &lacc[c * kD + half * 256 + lane * 4];
        atomicAdd(p + 0, acc[c].x);
        atomicAdd(p + 1, acc[c].y);
        atomicAdd(p + 2, acc[c].z);
        atomicAdd(p + 3, acc[c].w);
    }
    if (half == 0 && lane < kC) atomicAdd(&lcnt[lane], cacc);
    __syncthreads();
    for (int i = tid; i < kC * kD; i += 512) atomicAdd(&sums[i], lacc[i]);
    if (tid < kC) atomicAdd(&cnt[tid], lcnt[tid]);
}

// ---------------------------------------------------------------- K2: centroids, pair logic (1 block)
__global__ __launch_bounds__(256) void k2_cent(const float* __restrict__ sums,
                                               const float* __restrict__ cnt_g,
                                               float* __restrict__ cn_g,
                                               unsigned* __restrict__ mask_g,
                                               float* __restrict__ scal) {
    __shared__ __align__(16) float lcn[kC * kD];  // 32 KB
    __shared__ float lcnt[kC];
    __shared__ float red[256];
    __shared__ float norms[kC];
    __shared__ float pdm[kC * kC];
    int tid = threadIdx.x;
    if (tid < kC) lcnt[tid] = cnt_g[tid];
    __syncthreads();

    int c = tid >> 4, sub = tid & 15;
    float invc = 1.f / fmaxf(lcnt[c], 1.f);
    float sq = 0.f;
    for (int d = sub; d < kD; d += 16) {
        float v = sums[c * kD + d] * invc;
        lcn[c * kD + d] = v;
        sq += v * v;
    }
    red[tid] = sq;
    __syncthreads();
    if (tid < kC) {
        float t = 0.f;
        for (int k = 0; k < 16; ++k) t += red[tid * 16 + k];
        norms[tid] = fmaxf(sqrtf(t), kEps);
    }
    __syncthreads();
    for (int i = tid; i < kC * kD; i += 256) {
        float v = lcn[i] / norms[i / kD];
        lcn[i] = v;
        cn_g[i] = v;
    }
    __syncthreads();
    int pi = tid >> 4, pj = tid & 15;
    float dot = 0.f;
    for (int dd = 0; dd < kD; ++dd) {
        int d = (dd + tid) & (kD - 1);
        dot += lcn[pi * kD + d] * lcn[pj * kD + d];
    }
    pdm[tid] = 1.f - dot;
    __syncthreads();
    if (tid == 0) {
        unsigned m[kC];
        for (int a = 0; a < kC; ++a) m[a] = 0u;
        float npairs = 0.f;
        for (int a = 0; a < kC; ++a)
            for (int b = a + 1; b < kC; ++b) {
                bool close = (pdm[a * kC + b] <= kBeta) && (lcnt[a] > 0.f) && (lcnt[b] > 0.f);
                if (close) { m[a] |= 1u << b; m[b] |= 1u << a; npairs += 1.f; }
            }
        float count = 0.f;
        for (int a = 0; a < kC; ++a) {
            mask_g[a] = m[a];
            count += (float)__popc(m[a]) * lcnt[a];
        }
        scal[0] = fmaxf(count, 1.f);
        scal[1] = npairs;
    }
}

// ---------------------------------------------------------------- K3: main distance pass
// Centroids in REGISTERS (wreg[4][8]: lane = 4-class group g x dim-slice j),
// embeddings tiled through LDS (reg-buffered pipeline), one row per wave,
// 4-level shfl_xor butterfly over j only. No dynamic register indexing.
constexpr int TR = 32;   // tile rows; 32*2KB = 64 KB LDS
__global__ __launch_bounds__(512, 2) void k3_main(const float* __restrict__ emb,
                                                  const int* __restrict__ labels,
                                                  const float* __restrict__ cn_g,
                                                  const unsigned* __restrict__ mask_g,
                                                  float* __restrict__ total,
                                                  int N, int rpb) {
    __shared__ __align__(16) float4 xbuf[TR * 128];   // 64 KB
    __shared__ unsigned lmask[kC];
    __shared__ float wsum[8];
    int tid = threadIdx.x;
    int wave = tid >> 6, lane = tid & 63;
    int g = lane >> 4, j = lane & 15;

    // centroid fragment: class 4g+c, dims [64i+4j, 64i+4j+4)
    const float4* w4 = (const float4*)cn_g;
    float4 wreg[4][8];
#pragma unroll
    for (int c = 0; c < 4; ++c)
#pragma unroll
        for (int i = 0; i < 8; ++i)
            wreg[c][i] = w4[(4 * g + c) * 128 + i * 16 + j];
    if (tid < kC) lmask[tid] = mask_g[tid];

    int r0 = blockIdx.x * rpb;
    int r1 = min(r0 + rpb, N);
    float priv = 0.f;

    const float4* src = (const float4*)emb;
    float4 st[8];

    // prologue: load tile 0 into regs
    if (r0 < r1) {
        int avail = (r1 - r0) * 128;
#pragma unroll
        for (int k = 0; k < 8; ++k) {
            int idx = k * 512 + tid;
            st[k] = (idx < avail) ? src[(size_t)r0 * 128 + idx] : make_float4(0.f, 0.f, 0.f, 0.f);
        }
#pragma unroll
        for (int k = 0; k < 8; ++k) xbuf[k * 512 + tid] = st[k];
    }
    __syncthreads();

    for (int rt = r0; rt < r1; rt += TR) {
        int ntile = rt + TR;
        bool more = (ntile < r1);
        if (more) {
            int avail = (r1 - ntile) * 128;
#pragma unroll
            for (int k = 0; k < 8; ++k) {
                int idx = k * 512 + tid;
                st[k] = (idx < avail) ? src[(size_t)ntile * 128 + idx] : make_float4(0.f, 0.f, 0.f, 0.f);
            }
        }

        int rows = min(TR, r1 - rt);
        for (int rr = wave; rr < rows; rr += 8) {
            int row = rt + rr;
            int lab = labels[row];                 // uniform; scheduled early
            const float4* xr = &xbuf[rr * 128];
            float d0 = 0.f, d1 = 0.f, d2 = 0.f, d3 = 0.f, nrm = 0.f;
#pragma unroll
            for (int i = 0; i < 8; ++i) {
                float4 x = xr[i * 16 + j];         // 4-way broadcast across g
                nrm += dot4(x, x);
                d0 += dot4(x, wreg[0][i]);
                d1 += dot4(x, wreg[1][i]);
                d2 += dot4(x, wreg[2][i]);
                d3 += dot4(x, wreg[3][i]);
            }
#pragma unroll
            for (int m = 1; m < 16; m <<= 1) {
                d0 += __shfl_xor(d0, m, 64);
                d1 += __shfl_xor(d1, m, 64);
                d2 += __shfl_xor(d2, m, 64);
                d3 += __shfl_xor(d3, m, 64);
                nrm += __shfl_xor(nrm, m, 64);
            }
            if (j == 0) {
                unsigned mm = lmask[lab];
                float inv = 1.f / fmaxf(sqrtf(nrm), kEps);
                float s = 0.f;
                float dv[4] = {d0, d1, d2, d3};
#pragma unroll
                for (int c = 0; c < 4; ++c) {
                    int cg = 4 * g + c;
                    float dd = 1.f - dv[c] * inv;
                    if ((mm >> cg) & 1u) s += fmaxf(kBeta - dd, 0.f);
                    if (cg == lab) s += (float)__popc(mm) * fmaxf(dd - kAlpha, 0.f);
                }
                priv += s;
            }
        }
        __syncthreads();
        if (more) {
#pragma unroll
            for (int k = 0; k < 8; ++k) xbuf[k * 512 + tid] = st[k];
        }
        __syncthreads();
    }

    // block reduce
#pragma unroll
    for (int off = 32; off > 0; off >>= 1) priv += __shfl_down(priv, off, 64);
    if (lane == 0) wsum[wave] = priv;
    __syncthreads();
    if (tid == 0) {
        float t = 0.f;
#pragma unroll
        for (int w = 0; w < 8; ++w) t += wsum[w];
        atomicAdd(total, t);
    }
}

// ---------------------------------------------------------------- K4: epilogue
__global__ void k4_final(const float* __restrict__ total,
                         const float* __restrict__ scal,
                         float* __restrict__ out) {
    out[0] = (scal[1] > 0.f) ? (total[0] / scal[0]) : 0.f;
}

extern "C" void kernel_launch(void* const* d_in, const int* in_sizes, int n_in,
                              void* d_out, int out_size, void* d_ws, size_t ws_size,
                              hipStream_t stream) {
    const float* emb = (const float*)d_in[0];
    const int* labels = (const int*)d_in[1];
    int N = in_sizes[0] / kD;

    float* ws = (float*)d_ws;
    float* sums = ws + SUMS_OFF;
    float* cnt = ws + CNT_OFF;
    float* total = ws + TOT_OFF;
    float* cn = ws + CN_OFF;
    unsigned* mask = (unsigned*)(ws + MSK_OFF);
    float* scal = ws + SCL_OFF;

    hipMemsetAsync(d_ws, 0, ZERO_FLOATS * sizeof(float), stream);

    int blocks1 = 512;
    int rpb1 = (N + blocks1 - 1) / blocks1;
    k1_sums<<<blocks1, 512, 0, stream>>>(emb, labels, sums, cnt, N, rpb1);

    k2_cent<<<1, 256, 0, stream>>>(sums, cnt, cn, mask, scal);

    int blocks3 = 256;
    int rpb3 = (N + blocks3 - 1) / blocks3;
    k3_main<<<blocks3, 512, 0, stream>>>(emb, labels, cn, mask, total, N, rpb3);

    k4_final<<<1, 1, 0, stream>>>(total, scal, (float*)d_out);
}